// Round 1
// baseline (208.743 us; speedup 1.0000x reference)
//
#include <hip/hip_runtime.h>

#define DIMB 2
#define DIMS 192
#define HCHUNK 12   // 16 chunks of 12 rows cover h=0..191

// Compute 3x3 (w,d)-plane sums of the 5 product channels at row hh for the
// 4 output voxels (d0..d0+3) owned by this thread. Zero-padding semantics:
// out-of-range rows/cols/depths contribute 0.
__device__ __forceinline__ void compute_plane(
    const float* __restrict__ pred, const float* __restrict__ targ,
    int b, int hh, int w, int d0, float (&out)[5][4])
{
#pragma unroll
    for (int c = 0; c < 5; ++c)
#pragma unroll
        for (int j = 0; j < 4; ++j) out[c][j] = 0.f;
    if (hh < 0 || hh >= DIMS) return;

#pragma unroll
    for (int dw = -1; dw <= 1; ++dw) {
        const int wc = w + dw;
        if (wc < 0 || wc >= DIMS) continue;
        const size_t base = (((size_t)b * DIMS + hh) * DIMS + wc) * DIMS + d0;
        float p[6], t[6];
        const float4 p4 = *reinterpret_cast<const float4*>(pred + base);
        const float4 t4 = *reinterpret_cast<const float4*>(targ + base);
        p[1] = p4.x; p[2] = p4.y; p[3] = p4.z; p[4] = p4.w;
        t[1] = t4.x; t[2] = t4.y; t[3] = t4.z; t[4] = t4.w;
        p[0] = (d0 > 0)        ? pred[base - 1] : 0.f;
        t[0] = (d0 > 0)        ? targ[base - 1] : 0.f;
        p[5] = (d0 + 4 < DIMS) ? pred[base + 4] : 0.f;
        t[5] = (d0 + 4 < DIMS) ? targ[base + 4] : 0.f;
#pragma unroll
        for (int j = 0; j < 4; ++j) {
            out[0][j] += p[j] + p[j+1] + p[j+2];
            out[1][j] += t[j] + t[j+1] + t[j+2];
            out[2][j] += p[j]*p[j] + p[j+1]*p[j+1] + p[j+2]*p[j+2];
            out[3][j] += t[j]*t[j] + t[j+1]*t[j+1] + t[j+2]*t[j+2];
            out[4][j] += p[j]*t[j] + p[j+1]*t[j+1] + p[j+2]*t[j+2];
        }
    }
}

// One output row h: compute plane(h+1) into Pn, then emit ncc for the 4 voxels
// using window rows Pm=plane(h-1), Pc=plane(h), Pn=plane(h+1).
__device__ __forceinline__ float do_row(
    const float* __restrict__ pred, const float* __restrict__ targ,
    int b, int h, int w, int d0,
    float (&Pm)[5][4], float (&Pc)[5][4], float (&Pn)[5][4])
{
    compute_plane(pred, targ, b, h + 1, w, d0, Pn);
    const float inv = 1.0f / 27.0f;
    float acc = 0.f;
#pragma unroll
    for (int j = 0; j < 4; ++j) {
        const float sI  = Pm[0][j] + Pc[0][j] + Pn[0][j];
        const float sJ  = Pm[1][j] + Pc[1][j] + Pn[1][j];
        const float sII = Pm[2][j] + Pc[2][j] + Pn[2][j];
        const float sJJ = Pm[3][j] + Pc[3][j] + Pn[3][j];
        const float sIJ = Pm[4][j] + Pc[4][j] + Pn[4][j];
        // cross = kvol*(mIJ - mI*mJ) = sIJ - sI*sJ/27, etc.
        const float uI = sI * inv;
        const float uJ = sJ * inv;
        const float cross = sIJ - uI * sJ;
        const float pvar  = sII - uI * sI;
        const float tvar  = sJJ - uJ * sJ;
        acc += (cross * cross) / (tvar * pvar + 1e-5f);
    }
    return acc;
}

__global__ __launch_bounds__(256)
void FusedLocalNormalizedCrossCorrelationLoss_37838661877790_kernel(
    const float* __restrict__ pred, const float* __restrict__ targ,
    double* __restrict__ acc_out)
{
    const int tx = threadIdx.x;           // 16 d-quads
    const int ty = threadIdx.y;           // 16 w rows
    const int d0 = (blockIdx.x * 16 + tx) * 4;
    const int w  = blockIdx.y * 16 + ty;
    const int bz = blockIdx.z;
    const int b  = bz >> 4;               // 2 batches
    const int h0 = (bz & 15) * HCHUNK;    // 16 h-chunks

    float P[3][5][4];
    compute_plane(pred, targ, b, h0 - 1, w, d0, P[0]);
    compute_plane(pred, targ, b, h0,     w, d0, P[1]);

    float acc = 0.f;
    for (int hb = 0; hb < HCHUNK; hb += 3) {
        acc += do_row(pred, targ, b, h0 + hb,     w, d0, P[0], P[1], P[2]);
        acc += do_row(pred, targ, b, h0 + hb + 1, w, d0, P[1], P[2], P[0]);
        acc += do_row(pred, targ, b, h0 + hb + 2, w, d0, P[2], P[0], P[1]);
    }

    // Reduction: wave shuffle tree -> LDS -> one fp64 atomic per block.
#pragma unroll
    for (int off = 32; off > 0; off >>= 1)
        acc += __shfl_down(acc, off, 64);
    __shared__ float wacc[4];
    const int tid = ty * 16 + tx;
    if ((tid & 63) == 0) wacc[tid >> 6] = acc;
    __syncthreads();
    if (tid == 0) {
        const double s = (double)wacc[0] + (double)wacc[1]
                       + (double)wacc[2] + (double)wacc[3];
        atomicAdd(acc_out, s);
    }
}

__global__ void ncc_finalize(const double* __restrict__ acc,
                             float* __restrict__ out)
{
    const double n = (double)((size_t)DIMB * DIMS * DIMS * DIMS);
    out[0] = (float)(-acc[0] / n);
}

extern "C" void kernel_launch(void* const* d_in, const int* in_sizes, int n_in,
                              void* d_out, int out_size, void* d_ws, size_t ws_size,
                              hipStream_t stream) {
    const float* pred = (const float*)d_in[0];
    const float* targ = (const float*)d_in[1];
    double* acc = (double*)d_ws;

    hipMemsetAsync(d_ws, 0, sizeof(double), stream);

    dim3 block(16, 16, 1);
    dim3 grid(3 /* 48 d-quads / 16 */, 12 /* 192/16 w */, DIMB * 16 /* h-chunks */);
    FusedLocalNormalizedCrossCorrelationLoss_37838661877790_kernel
        <<<grid, block, 0, stream>>>(pred, targ, acc);
    ncc_finalize<<<1, 1, 0, stream>>>(acc, (float*)d_out);
}